// Round 14
// baseline (395.531 us; speedup 1.0000x reference)
//
#include <hip/hip_runtime.h>
#include <hip/hip_cooperative_groups.h>

namespace cg = cooperative_groups;

#define NLAT 361
#define NLON 720
#define LMAX 360
#define MMAX 361

#define NSL  5                         // n slices (905 virtual dft blocks <= 1024)
#define QSL  73                        // slice width; last slice cnt = 69
#define SL_F (MMAX * NLAT * 8)         // 1,042,568 floats per slice / XE / xt
#define NVB_DFT (181 * NSL)            // 905
#define NVB_CON (12 * MMAX)            // 4332
#define GRID_B 1024

static constexpr float kAngF = 8.72664625997164788e-3f;  // 2*pi/720

// ---------------- phase 1: fold x into XE[k][n][8ch] ----------------
__device__ __forceinline__ void d_fold(const float* __restrict__ x,
                                       float* __restrict__ XE,
                                       int gtid, int gsz) {
    for (int j = gtid; j < NLAT * NLAT; j += gsz) {
        int k = j / NLAT, n = j - k * NLAT;
        float v[8];
#pragma unroll
        for (int ch = 0; ch < 8; ++ch) {
            const float* __restrict__ row = x + ((size_t)ch * NLAT + k) * NLON;
            float a = row[n];
            float b = (n == 0) ? 0.f : row[NLON - n];   // n=360 -> 2*x[360]; fixup later
            v[ch] = a + b;
        }
        float4* o = (float4*)(XE + (size_t)j * 8);
        o[0] = make_float4(v[0], v[1], v[2], v[3]);
        o[1] = make_float4(v[4], v[5], v[6], v[7]);
    }
}

// ---------------- phase 2: DFT, one virtual block (bx, nq) ----------------
// slice[nq][m,k,ch] = sum_{n in slice} cos(n*m*th) * XE[k,n,ch]
__device__ __forceinline__ void d_dft_vb(const float* __restrict__ XE,
                                         float* __restrict__ slices,
                                         int vb, int tid) {
    const int bx = vb % 181, nq = vb / 181;
    const int ks = tid >> 7, ml = tid & 127;
    const int n0 = nq * QSL;
    const int cnt = (nq == NSL - 1) ? (NLAT - n0) : QSL;
    const int k  = bx * 2 + ks;
    const int kc = (k <= 360) ? k : 360;
    const float* __restrict__ xr = XE + ((size_t)kc * NLAT + n0) * 8;

    int mm[3];
    mm[0] = ml; mm[1] = ml + 128;
    const bool m2v = (ml + 256 <= 360);
    mm[2] = m2v ? (ml + 256) : 360;

    float P0[3], P1[3], c2v[3];
#pragma unroll
    for (int q = 0; q < 3; ++q) {
        int t0 = (n0 * mm[q]) % NLON;                 // exact integer reduction
        int t1 = t0 + mm[q]; if (t1 >= NLON) t1 -= NLON;
        P0[q]  = __cosf((float)t0 * kAngF);
        P1[q]  = __cosf((float)t1 * kAngF);
        c2v[q] = 2.f * __cosf((float)mm[q] * kAngF);
    }

    float acc[3][8];
#pragma unroll
    for (int q = 0; q < 3; ++q)
#pragma unroll
        for (int b = 0; b < 8; ++b) acc[q][b] = 0.f;

#pragma unroll 4
    for (int nn = 0; nn < cnt; ++nn) {
        float4 e0 = *(const float4*)(xr + nn * 8);        // wave-uniform -> 1 req
        float4 e1 = *(const float4*)(xr + nn * 8 + 4);
#pragma unroll
        for (int q = 0; q < 3; ++q) {
            float f = P0[q];
            acc[q][0] += f * e0.x;  acc[q][1] += f * e0.y;
            acc[q][2] += f * e0.z;  acc[q][3] += f * e0.w;
            acc[q][4] += f * e1.x;  acc[q][5] += f * e1.y;
            acc[q][6] += f * e1.z;  acc[q][7] += f * e1.w;
            float Pn = c2v[q] * P1[q] - P0[q];
            P0[q] = P1[q];
            P1[q] = Pn;
        }
    }

    if (nq == NSL - 1) {     // n=360 got weight 1*(-1)^m * (2x); correct to 0.5
        const float4 e0 = *(const float4*)(xr + (360 - n0) * 8);
        const float4 e1 = *(const float4*)(xr + (360 - n0) * 8 + 4);
#pragma unroll
        for (int q = 0; q < 3; ++q) {
            float h = 0.5f * ((mm[q] & 1) ? -1.f : 1.f);
            acc[q][0] -= h * e0.x;  acc[q][1] -= h * e0.y;
            acc[q][2] -= h * e0.z;  acc[q][3] -= h * e0.w;
            acc[q][4] -= h * e1.x;  acc[q][5] -= h * e1.y;
            acc[q][6] -= h * e1.z;  acc[q][7] -= h * e1.w;
        }
    }

#pragma unroll
    for (int q = 0; q < 3; ++q)
#pragma unroll
        for (int b = 0; b < 8; ++b) acc[q][b] *= kAngF;

    if (k <= 360) {
        float4* __restrict__ o4 = (float4*)(slices + (size_t)nq * SL_F);
#pragma unroll
        for (int q = 0; q < 3; ++q) {
            if (q == 2 && !m2v) break;
            int b0 = (mm[q] * NLAT + k) * 2;
            o4[b0]     = make_float4(acc[q][0], acc[q][1], acc[q][2], acc[q][3]);
            o4[b0 + 1] = make_float4(acc[q][4], acc[q][5], acc[q][6], acc[q][7]);
        }
    }
}

// ---------------- phase 3: sum NSL slices ----------------
__device__ __forceinline__ void d_red(const float* __restrict__ slices,
                                      float4* __restrict__ xt,
                                      int gtid, int gsz) {
    const float4* q4 = (const float4*)slices;
    for (int i = gtid; i < SL_F / 4; i += gsz) {
        float4 s = q4[i];
#pragma unroll
        for (int u = 1; u < NSL; ++u) {
            float4 a = q4[i + (size_t)u * (SL_F / 4)];
            s.x += a.x; s.y += a.y; s.z += a.z; s.w += a.w;
        }
        xt[i] = s;
    }
}

// ---------------- phase 4: contraction, one virtual block (m, lt) ----------------
__device__ __forceinline__ void d_con_vb(const float* __restrict__ W,
                                         const float* __restrict__ xt,
                                         float* __restrict__ out,
                                         int vb, int tid) {
    const int m  = vb / 12;
    const int lt = vb % 12;
    const int l0 = lt * 32;

    if (l0 + 31 < m) {                     // tile fully below diagonal
        int l = l0 + (tid >> 3), bc = tid & 7;
        out[(bc * LMAX + l) * MMAX + m] = 0.f;
        return;
    }

    const int kk = tid & 31, lq = tid >> 5;
    const int lb = l0 + lq * 4;

    int lr[4];
#pragma unroll
    for (int j = 0; j < 4; ++j) {
        int l = lb + j;
        if (l < m)        l = m;           // dedup discarded rows onto row m
        if (l > LMAX - 1) l = LMAX - 1;
        lr[j] = l;
    }

    const float* __restrict__ Wm = W + (size_t)m * (LMAX * NLAT);
    const float* __restrict__ r0 = Wm + lr[0] * NLAT + kk;
    const float* __restrict__ r1 = Wm + lr[1] * NLAT + kk;
    const float* __restrict__ r2 = Wm + lr[2] * NLAT + kk;
    const float* __restrict__ r3 = Wm + lr[3] * NLAT + kk;

    float wv[12][4];
#pragma unroll
    for (int t = 0; t < 11; ++t) {
        wv[t][0] = r0[t * 32];
        wv[t][1] = r1[t * 32];
        wv[t][2] = r2[t * 32];
        wv[t][3] = r3[t * 32];
    }
    {
        int kq = 11 * 32 + kk;
        int kc = (kq <= 360) ? kq : 360;
        wv[11][0] = Wm[lr[0] * NLAT + kc];
        wv[11][1] = Wm[lr[1] * NLAT + kc];
        wv[11][2] = Wm[lr[2] * NLAT + kc];
        wv[11][3] = Wm[lr[3] * NLAT + kc];
        if (kq > 360) { wv[11][0] = wv[11][1] = wv[11][2] = wv[11][3] = 0.f; }
    }

    float v[32];
#pragma unroll
    for (int i = 0; i < 32; ++i) v[i] = 0.f;

    const float4* __restrict__ xt4 = (const float4*)xt;
#pragma unroll
    for (int t = 0; t < 12; ++t) {
        int kq = t * 32 + kk;
        int kc = (kq <= 360) ? kq : 360;
        int xb = (m * NLAT + kc) * 2;
        float4 x0 = xt4[xb], x1 = xt4[xb + 1];
#pragma unroll
        for (int j = 0; j < 4; ++j) {
            float wj = wv[t][j];
            v[j*8 + 0] += wj * x0.x;  v[j*8 + 1] += wj * x0.y;
            v[j*8 + 2] += wj * x0.z;  v[j*8 + 3] += wj * x0.w;
            v[j*8 + 4] += wj * x1.x;  v[j*8 + 5] += wj * x1.y;
            v[j*8 + 6] += wj * x1.z;  v[j*8 + 7] += wj * x1.w;
        }
    }

#define RSTEP(MASK, CNT) { const bool hi = (kk & MASK) != 0; \
    _Pragma("unroll") \
    for (int i = 0; i < CNT; ++i) { \
        float keep = hi ? v[i + CNT] : v[i]; \
        float send = hi ? v[i] : v[i + CNT]; \
        v[i] = keep + __shfl_xor(send, MASK); } }
    RSTEP(16, 16) RSTEP(8, 8) RSTEP(4, 4) RSTEP(2, 2) RSTEP(1, 1)
#undef RSTEP

    int j  = kk >> 3;
    int bc = kk & 7;
    int l  = l0 + lq * 4 + j;
    if (l >= LMAX) return;
    float r = (l < m) ? 0.f : v[0];
    out[(bc * LMAX + l) * MMAX + m] = r;
}

// ---------------- fused cooperative kernel ----------------
__global__ __launch_bounds__(256, 4) void k_fused(const float* __restrict__ x,
                                                  const float* __restrict__ W,
                                                  float* __restrict__ ws,
                                                  float* __restrict__ out) {
    cg::grid_group grid = cg::this_grid();
    const int tid  = threadIdx.x;
    const int bid  = blockIdx.x;
    const int nb   = gridDim.x;
    const int gtid = bid * 256 + tid;
    const int gsz  = nb * 256;

    float* XE     = ws;
    float* slices = ws + (size_t)SL_F;
    float* xt     = ws + (size_t)(1 + NSL) * SL_F;

    d_fold(x, XE, gtid, gsz);
    grid.sync();

    for (int vb = bid; vb < NVB_DFT; vb += nb)
        d_dft_vb(XE, slices, vb, tid);
    grid.sync();

    d_red(slices, (float4*)xt, gtid, gsz);
    grid.sync();

    for (int vb = bid; vb < NVB_CON; vb += nb)
        d_con_vb(W, xt, out, vb, tid);
}

// ---------------- fallback standalone kernels (same math) ----------------
__global__ __launch_bounds__(256) void k_fold_s(const float* __restrict__ x,
                                                float* __restrict__ ws) {
    d_fold(x, ws, blockIdx.x * 256 + threadIdx.x, gridDim.x * 256);
}
__global__ __launch_bounds__(256, 4) void k_dft_s(float* __restrict__ ws) {
    d_dft_vb(ws, ws + (size_t)SL_F, blockIdx.x, threadIdx.x);
}
__global__ __launch_bounds__(256) void k_red_s(float* __restrict__ ws) {
    d_red(ws + (size_t)SL_F, (float4*)(ws + (size_t)(1 + NSL) * SL_F),
          blockIdx.x * 256 + threadIdx.x, gridDim.x * 256);
}
__global__ __launch_bounds__(256) void k_con_s(const float* __restrict__ W,
                                               float* __restrict__ ws,
                                               float* __restrict__ out) {
    d_con_vb(W, ws + (size_t)(1 + NSL) * SL_F, out, blockIdx.x, threadIdx.x);
}

extern "C" void kernel_launch(void* const* d_in, const int* in_sizes, int n_in,
                              void* d_out, int out_size, void* d_ws, size_t ws_size,
                              hipStream_t stream) {
    const float* x = (const float*)d_in[0];
    const float* W = (const float*)d_in[1];
    float* ws  = (float*)d_ws;
    float* out = (float*)d_out;

    // try the fused cooperative kernel first
    void* args[] = { (void*)&x, (void*)&W, (void*)&ws, (void*)&out };
    hipError_t e = hipLaunchCooperativeKernel((const void*)k_fused,
                                              dim3(GRID_B), dim3(256),
                                              args, 0, stream);
    if (e == hipSuccess) return;
    (void)hipGetLastError();   // clear sticky error, fall back to plain kernels

    k_fold_s<<<dim3((NLAT * NLAT + 255) / 256), dim3(256), 0, stream>>>(x, ws);
    k_dft_s<<<dim3(NVB_DFT), dim3(256), 0, stream>>>(ws);
    k_red_s<<<dim3((SL_F / 4 + 255) / 256), dim3(256), 0, stream>>>(ws);
    k_con_s<<<dim3(NVB_CON), dim3(256), 0, stream>>>(W, ws, out);
}

// Round 15
// 58.392 us; speedup vs baseline: 6.7737x; 6.7737x over previous
//
#include <hip/hip_runtime.h>

#define NLAT 361
#define NLON 720
#define LMAX 360
#define MMAX 361

#define NSL  4                         // n slices
#define QSL  91                        // slice width (last = 88)
#define SL_F (NLAT * MMAX * 8)         // 1,042,568 floats per slice

static constexpr float kAngF = 8.72664625997164788e-3f;  // 2*pi/720

// ---------------- kernel 1: DFT. block = 4 k-waves x 64 m-lanes, 6 m/thread ----
// slice[nq][k][m][8ch] = sum_{n in slice} cos(n*m*th) * (x[n]+x[720-n])
// Writes coalesced (lanes along m). Chebyshev recurrence, reseeded per slice.
__global__ __launch_bounds__(256) void k_dft7(const float* __restrict__ x,
                                              float* __restrict__ slices) {
    const int bx  = blockIdx.x;        // k-tile: k = bx*4 + w
    const int nq  = blockIdx.y;        // n slice
    const int tid = threadIdx.x;
    const int w   = tid >> 6;          // wave = k slot
    const int ml  = tid & 63;          // m lane
    const int n0  = nq * QSL;
    const int cnt = min(QSL, NLAT - n0);   // 91,91,91,88

    __shared__ __align__(16) float xe[4][QSL][8];   // 11.6 KB

    // fold (nn fastest -> coalesced fwd & mirror x reads)
    for (int j = tid; j < 4 * 8 * QSL; j += 256) {
        int s  = j / (8 * QSL);
        int r  = j - s * (8 * QSL);
        int ch = r / QSL;
        int nn = r - ch * QSL;
        int k  = bx * 4 + s;
        int n  = n0 + nn;
        float v = 0.f;
        if (nn < cnt && k <= 360) {
            const float* __restrict__ row = x + ((size_t)ch * NLAT + k) * NLON;
            float a = row[n];
            float b = (n == 0) ? 0.f : row[NLON - n];   // n=360 -> 2x; fixup below
            v = a + b;
        }
        xe[s][nn][ch] = v;
    }
    __syncthreads();

    float P0[6], P1[6], c2[6];
#pragma unroll
    for (int q = 0; q < 6; ++q) {
        int m = ml + 64 * q; if (m > 360) m = 360;      // clamp (store guarded)
        int t0 = (n0 * m) % NLON;                       // exact integer reduction
        int t1 = t0 + m; if (t1 >= NLON) t1 -= NLON;
        P0[q] = __cosf((float)t0 * kAngF);
        P1[q] = __cosf((float)t1 * kAngF);
        c2[q] = 2.f * __cosf((float)m * kAngF);
    }

    float acc[6][8];
#pragma unroll
    for (int q = 0; q < 6; ++q)
#pragma unroll
        for (int b = 0; b < 8; ++b) acc[q][b] = 0.f;

#pragma unroll 2
    for (int nn = 0; nn < cnt; ++nn) {
        float4 e0 = *(const float4*)&xe[w][nn][0];      // wave-uniform broadcast
        float4 e1 = *(const float4*)&xe[w][nn][4];
#pragma unroll
        for (int q = 0; q < 6; ++q) {
            float f = P0[q];
            acc[q][0] += f * e0.x;  acc[q][1] += f * e0.y;
            acc[q][2] += f * e0.z;  acc[q][3] += f * e0.w;
            acc[q][4] += f * e1.x;  acc[q][5] += f * e1.y;
            acc[q][6] += f * e1.z;  acc[q][7] += f * e1.w;
            float Pn = c2[q] * P1[q] - P0[q];
            P0[q] = P1[q];
            P1[q] = Pn;
        }
    }

    if (nq == NSL - 1) {      // n=360 (nn=87): weight 1*(-1)^m*(2x) -> 0.5
        float4 e0 = *(const float4*)&xe[w][87][0];
        float4 e1 = *(const float4*)&xe[w][87][4];
#pragma unroll
        for (int q = 0; q < 6; ++q) {
            int m = ml + 64 * q;
            float h = 0.5f * ((m & 1) ? -1.f : 1.f);
            acc[q][0] -= h * e0.x;  acc[q][1] -= h * e0.y;
            acc[q][2] -= h * e0.z;  acc[q][3] -= h * e0.w;
            acc[q][4] -= h * e1.x;  acc[q][5] -= h * e1.y;
            acc[q][6] -= h * e1.z;  acc[q][7] -= h * e1.w;
        }
    }

    const int k = bx * 4 + w;
    if (k <= 360) {
        float* __restrict__ sl = slices + (size_t)nq * SL_F;
#pragma unroll
        for (int q = 0; q < 6; ++q) {
            int m = ml + 64 * q;
            if (m > 360) continue;
            float4* o = (float4*)(sl + ((size_t)k * MMAX + m) * 8);
            o[0] = make_float4(acc[q][0] * kAngF, acc[q][1] * kAngF,
                               acc[q][2] * kAngF, acc[q][3] * kAngF);
            o[1] = make_float4(acc[q][4] * kAngF, acc[q][5] * kAngF,
                               acc[q][6] * kAngF, acc[q][7] * kAngF);
        }
    }
}

// ---------------- kernel 2: sum NSL slices + transpose [k][m] -> [m][k] --------
#define TK 16
#define TM 32
#define TSTRIDE 265                    // LDS row stride (floats), conflict-breaking
__global__ __launch_bounds__(256) void k_redT(const float* __restrict__ slices,
                                              float* __restrict__ xt) {
    const int k0  = blockIdx.x * TK;
    const int m0  = blockIdx.y * TM;
    const int tid = threadIdx.x;

    __shared__ __align__(16) float t[TK * TSTRIDE];   // 17 KB

    // phase 1: accumulate 4 slices, reads coalesced (lanes along m,ch)
    for (int j = tid; j < TK * TM * 2; j += 256) {    // float4 units
        int kk = j / (TM * 2);
        int r  = j - kk * (TM * 2);
        int mm = r >> 1, h = r & 1;
        int k = k0 + kk, m = m0 + mm;
        float4 s = make_float4(0.f, 0.f, 0.f, 0.f);
        if (k <= 360 && m <= 360) {
            size_t off = ((size_t)k * MMAX + m) * 2 + h;
            const float4* p = (const float4*)slices;
#pragma unroll
            for (int q = 0; q < NSL; ++q) {
                float4 a = p[off + (size_t)q * (SL_F / 4)];
                s.x += a.x; s.y += a.y; s.z += a.z; s.w += a.w;
            }
        }
        *(float4*)&t[kk * TSTRIDE + mm * 8 + h * 4] = s;
    }
    __syncthreads();

    // phase 2: write xt[m][k][8], coalesced (lanes along k,ch)
    for (int j = tid; j < TM * TK * 2; j += 256) {
        int mm = j / (TK * 2);
        int r  = j - mm * (TK * 2);
        int kk = r >> 1, h = r & 1;
        int k = k0 + kk, m = m0 + mm;
        if (k <= 360 && m <= 360) {
            float4 v = *(const float4*)&t[kk * TSTRIDE + mm * 8 + h * 4];
            ((float4*)xt)[((size_t)m * MMAX + k) * 2 + h] = v;
        }
    }
}

// ---------------- kernel 3: contraction (unchanged, proven ~8 us) --------------
__global__ __launch_bounds__(256) void k_contract4(const float* __restrict__ W,
                                                   const float* __restrict__ xt,
                                                   float* __restrict__ out) {
    const int lt   = blockIdx.x;
    const int m    = blockIdx.y;
    const int l0   = lt * 32;
    const int tid  = threadIdx.x;

    if (l0 + 31 < m) {
        int l = l0 + (tid >> 3), bc = tid & 7;
        out[(bc * LMAX + l) * MMAX + m] = 0.f;
        return;
    }

    const int kk = tid & 31, lq = tid >> 5;
    const int lb = l0 + lq * 4;

    int lr[4];
#pragma unroll
    for (int j = 0; j < 4; ++j) {
        int l = lb + j;
        if (l < m)        l = m;
        if (l > LMAX - 1) l = LMAX - 1;
        lr[j] = l;
    }

    const float* __restrict__ Wm = W + (size_t)m * (LMAX * NLAT);
    const float* __restrict__ r0 = Wm + lr[0] * NLAT + kk;
    const float* __restrict__ r1 = Wm + lr[1] * NLAT + kk;
    const float* __restrict__ r2 = Wm + lr[2] * NLAT + kk;
    const float* __restrict__ r3 = Wm + lr[3] * NLAT + kk;

    float wv[12][4];
#pragma unroll
    for (int t = 0; t < 11; ++t) {
        wv[t][0] = r0[t * 32];
        wv[t][1] = r1[t * 32];
        wv[t][2] = r2[t * 32];
        wv[t][3] = r3[t * 32];
    }
    {
        int kq = 11 * 32 + kk;
        int kc = (kq <= 360) ? kq : 360;
        wv[11][0] = Wm[lr[0] * NLAT + kc];
        wv[11][1] = Wm[lr[1] * NLAT + kc];
        wv[11][2] = Wm[lr[2] * NLAT + kc];
        wv[11][3] = Wm[lr[3] * NLAT + kc];
        if (kq > 360) { wv[11][0] = wv[11][1] = wv[11][2] = wv[11][3] = 0.f; }
    }

    float v[32];
#pragma unroll
    for (int i = 0; i < 32; ++i) v[i] = 0.f;

    const float4* __restrict__ xt4 = (const float4*)xt;
#pragma unroll
    for (int t = 0; t < 12; ++t) {
        int kq = t * 32 + kk;
        int kc = (kq <= 360) ? kq : 360;
        int xb = (m * NLAT + kc) * 2;
        float4 x0 = xt4[xb], x1 = xt4[xb + 1];
#pragma unroll
        for (int j = 0; j < 4; ++j) {
            float wj = wv[t][j];
            v[j*8 + 0] += wj * x0.x;  v[j*8 + 1] += wj * x0.y;
            v[j*8 + 2] += wj * x0.z;  v[j*8 + 3] += wj * x0.w;
            v[j*8 + 4] += wj * x1.x;  v[j*8 + 5] += wj * x1.y;
            v[j*8 + 6] += wj * x1.z;  v[j*8 + 7] += wj * x1.w;
        }
    }

#define RSTEP(MASK, CNT) { const bool hi = (kk & MASK) != 0; \
    _Pragma("unroll") \
    for (int i = 0; i < CNT; ++i) { \
        float keep = hi ? v[i + CNT] : v[i]; \
        float send = hi ? v[i] : v[i + CNT]; \
        v[i] = keep + __shfl_xor(send, MASK); } }
    RSTEP(16, 16) RSTEP(8, 8) RSTEP(4, 4) RSTEP(2, 2) RSTEP(1, 1)
#undef RSTEP

    int j  = kk >> 3;
    int bc = kk & 7;
    int l  = l0 + lq * 4 + j;
    if (l >= LMAX) return;
    float r = (l < m) ? 0.f : v[0];
    out[(bc * LMAX + l) * MMAX + m] = r;
}

// ---------------- legacy fallback (cplx hedge / small ws) ----------------
template<int CPLX>
__global__ __launch_bounds__(192) void k_dft_leg(const float* __restrict__ x,
                                                 float* __restrict__ xt,
                                                 int mb, int mc) {
    const int k    = blockIdx.x;
    const int half = blockIdx.y;
    const int tid  = threadIdx.x;

    __shared__ __align__(16) float  xr[8 * 724];
    __shared__ __align__(16) float2 exo[8 * 362];

    {
        const float4* __restrict__ x4 = (const float4*)x;
        for (int j = tid; j < 8 * 180; j += 192) {
            int b = j / 180, q = j - b * 180;
            ((float4*)&xr[b * 724])[q] = x4[(b * NLAT + k) * 180 + q];
        }
        if (tid < 8) ((float4*)&xr[tid * 724])[180] = make_float4(0.f, 0.f, 0.f, 0.f);
    }
    __syncthreads();

    for (int j = tid; j < 8 * NLAT; j += 192) {
        int b = j / NLAT, n = j - b * NLAT;
        float xa  = xr[b * 724 + n];
        float xbv = xr[b * 724 + (NLON - n)];
        exo[b * 362 + n] = make_float2(xa + xbv, xa - xbv);
    }
    __syncthreads();

    const int  m_local = half * 192 + tid;
    const bool valid   = (m_local < mc);
    const int  m       = mb + (valid ? m_local : 0);

    float aRe[8], aIm[8];
#pragma unroll
    for (int b = 0; b < 8; ++b) { aRe[b] = 0.f; aIm[b] = 0.f; }

    int tacc = 0;
    for (int n = 0; n < NLAT; ++n) {
        float sn, cs;
        __sincosf((float)tacc * kAngF, &sn, &cs);
        float wgt = (n == 360) ? 0.5f : 1.0f;
        float fc = wgt * kAngF * cs;
        float fs = -wgt * kAngF * sn;
        tacc += m;
        if (tacc >= NLON) tacc -= NLON;
#pragma unroll
        for (int b = 0; b < 8; ++b) {
            float2 e = exo[b * 362 + n];
            aRe[b] += fc * e.x;
            if (CPLX) aIm[b] += fs * e.y;
        }
    }

    if (valid) {
        float4* __restrict__ xt4 = (float4*)xt;
        if (CPLX) {
            int base = (m_local * NLAT + k) * 4;
#pragma unroll
            for (int q = 0; q < 4; ++q)
                xt4[base + q] = make_float4(aRe[2*q], aIm[2*q], aRe[2*q+1], aIm[2*q+1]);
        } else {
            int base = (m_local * NLAT + k) * 2;
            xt4[base + 0] = make_float4(aRe[0], aRe[1], aRe[2], aRe[3]);
            xt4[base + 1] = make_float4(aRe[4], aRe[5], aRe[6], aRe[7]);
        }
    }
}

template<int CPLX>
__global__ __launch_bounds__(256) void k_contract_leg(const float* __restrict__ W,
                                                      const float* __restrict__ xt,
                                                      float* __restrict__ out,
                                                      int mb) {
    const int lt   = blockIdx.x;
    const int mloc = blockIdx.y;
    const int m    = mb + mloc;
    const int l0   = lt * 32;
    const int tid  = threadIdx.x;

    if (l0 + 31 < m) {
        int l = l0 + (tid >> 3), bc = tid & 7;
        int idx = (bc * LMAX + l) * MMAX + m;
        if (CPLX) ((float2*)out)[idx] = make_float2(0.f, 0.f);
        else      out[idx] = 0.f;
        return;
    }

    const int kk = tid & 31, lq = tid >> 5;
    const int lb = l0 + lq * 4;

    int lr[4];
#pragma unroll
    for (int j = 0; j < 4; ++j) {
        int l = lb + j;
        if (l < m)        l = m;
        if (l > LMAX - 1) l = LMAX - 1;
        lr[j] = l;
    }

    const float* __restrict__ Wm = W + (size_t)m * (LMAX * NLAT);
    const float4* __restrict__ xt4 = (const float4*)xt;
    constexpr int NX = CPLX ? 4 : 2;
    constexpr int NV = CPLX ? 64 : 32;

    float v[NV];
#pragma unroll
    for (int i = 0; i < NV; ++i) v[i] = 0.f;

#define CLOAD(T, WV, XV) { \
    int kq = (T) * 32 + kk; \
    int kc = (kq < NLAT) ? kq : (NLAT - 1); \
    _Pragma("unroll") \
    for (int j = 0; j < 4; ++j) WV[j] = Wm[lr[j] * NLAT + kc]; \
    int xb = (mloc * NLAT + kc) * NX; \
    _Pragma("unroll") \
    for (int q = 0; q < NX; ++q) XV[q] = xt4[xb + q]; \
    if (kq >= NLAT) { WV[0] = WV[1] = WV[2] = WV[3] = 0.f; } }

#define CFMA(WV, XV) { \
    _Pragma("unroll") \
    for (int j = 0; j < 4; ++j) { \
        float wj = WV[j]; \
        if (CPLX) { \
            _Pragma("unroll") \
            for (int q = 0; q < 4; ++q) { \
                v[j*16 + (2*q  )*2 + 0] += wj * XV[q].x; \
                v[j*16 + (2*q  )*2 + 1] += wj * XV[q].y; \
                v[j*16 + (2*q+1)*2 + 0] += wj * XV[q].z; \
                v[j*16 + (2*q+1)*2 + 1] += wj * XV[q].w; \
            } \
        } else { \
            v[j*8 + 0] += wj * XV[0].x;  v[j*8 + 1] += wj * XV[0].y; \
            v[j*8 + 2] += wj * XV[0].z;  v[j*8 + 3] += wj * XV[0].w; \
            v[j*8 + 4] += wj * XV[1].x;  v[j*8 + 5] += wj * XV[1].y; \
            v[j*8 + 6] += wj * XV[1].z;  v[j*8 + 7] += wj * XV[1].w; \
        } \
    } }

    float  w0[4], w1[4], wn[4];
    float4 x0[NX], x1[NX], xn[NX];
    CLOAD(0, w0, x0)
    CLOAD(1, w1, x1)
#pragma unroll
    for (int t = 0; t < 12; ++t) {
        if (t < 10) CLOAD(t + 2, wn, xn)
        CFMA(w0, x0)
#pragma unroll
        for (int j = 0; j < 4; ++j) w0[j] = w1[j];
#pragma unroll
        for (int q = 0; q < NX; ++q) x0[q] = x1[q];
        if (t < 10) {
#pragma unroll
            for (int j = 0; j < 4; ++j) w1[j] = wn[j];
#pragma unroll
            for (int q = 0; q < NX; ++q) x1[q] = xn[q];
        }
    }
#undef CLOAD
#undef CFMA

#define RSTEP(MASK, CNT) { const bool hi = (kk & MASK) != 0; \
    _Pragma("unroll") \
    for (int i = 0; i < CNT; ++i) { \
        float keep = hi ? v[i + CNT] : v[i]; \
        float send = hi ? v[i] : v[i + CNT]; \
        v[i] = keep + __shfl_xor(send, MASK); } }
    if (CPLX) {
        RSTEP(16, 32) RSTEP(8, 16) RSTEP(4, 8) RSTEP(2, 4) RSTEP(1, 2)
    } else {
        RSTEP(16, 16) RSTEP(8, 8) RSTEP(4, 4) RSTEP(2, 2) RSTEP(1, 1)
    }
#undef RSTEP

    int j  = kk >> 3;
    int bc = kk & 7;
    int l  = l0 + lq * 4 + j;
    if (l >= LMAX) return;
    int idx = (bc * LMAX + l) * MMAX + m;
    if (CPLX) {
        float2 r = make_float2(v[0], v[1]);
        if (l < m) r = make_float2(0.f, 0.f);
        ((float2*)out)[idx] = r;
    } else {
        float r = (l < m) ? 0.f : v[0];
        out[idx] = r;
    }
}

extern "C" void kernel_launch(void* const* d_in, const int* in_sizes, int n_in,
                              void* d_out, int out_size, void* d_ws, size_t ws_size,
                              hipStream_t stream) {
    const float* x = (const float*)d_in[0];
    const float* W = (const float*)d_in[1];
    float* ws = (float*)d_ws;

    const int n_complex = 8 * LMAX * MMAX;            // 1,039,680
    const int cplx = (out_size >= 2 * n_complex) ? 1 : 0;

    if (!cplx && ws_size >= (size_t)(NSL + 1) * SL_F * sizeof(float)) {
        float* slices = ws;
        float* xt     = ws + (size_t)NSL * SL_F;
        k_dft7<<<dim3(91, NSL), dim3(256), 0, stream>>>(x, slices);
        k_redT<<<dim3(23, 12), dim3(256), 0, stream>>>(slices, xt);
        k_contract4<<<dim3(12, MMAX), dim3(256), 0, stream>>>(W, xt, (float*)d_out);
        return;
    }

    // hedge / fallback: legacy sincosf path (chunked if ws small)
    const int xs_per_mk = cplx ? 16 : 8;
    const size_t per_m_bytes = (size_t)NLAT * xs_per_mk * sizeof(float);
    int CM = (int)(ws_size / per_m_bytes);
    if (CM > MMAX) CM = MMAX;
    if (CM < 1)    CM = 1;
    for (int mbase = 0; mbase < MMAX; mbase += CM) {
        int mc = MMAX - mbase;
        if (mc > CM) mc = CM;
        if (cplx) {
            k_dft_leg<1><<<dim3(NLAT, (mc + 191) / 192), dim3(192), 0, stream>>>(
                x, ws, mbase, mc);
            k_contract_leg<1><<<dim3(12, mc), dim3(256), 0, stream>>>(W, ws, (float*)d_out, mbase);
        } else {
            k_dft_leg<0><<<dim3(NLAT, (mc + 191) / 192), dim3(192), 0, stream>>>(
                x, ws, mbase, mc);
            k_contract_leg<0><<<dim3(12, mc), dim3(256), 0, stream>>>(W, ws, (float*)d_out, mbase);
        }
    }
}

// Round 16
// 56.421 us; speedup vs baseline: 7.0104x; 1.0349x over previous
//
#include <hip/hip_runtime.h>

#define NLAT 361
#define NLON 720
#define LMAX 360
#define MMAX 361

#define NSL  8                         // n slices
#define QSL  46                        // slice width (slice 7: 39)
#define SL_F (NLAT * MMAX * 8)         // 1,042,568 floats per slice

static constexpr float kAngF = 8.72664625997164788e-3f;  // 2*pi/720

// ---------------- kernel 1: DFT ----------------
// block 256 = 4 waves = (2 k-slots) x (2 n-halves); wave = 64 m-lanes x 6 m.
// slice[nq][k][m][8ch] = sum_{n in slice} cos(n*m*th)*(x[n]+x[720-n])
// grid (181, 4): k = bx*2 + ks, nq = by*2 + nh.
__global__ __launch_bounds__(256) void k_dft9(const float* __restrict__ x,
                                              float* __restrict__ slices) {
    const int bx  = blockIdx.x;
    const int by  = blockIdx.y;
    const int tid = threadIdx.x;
    const int w   = tid >> 6;          // wave 0..3
    const int ks  = w & 1;             // k slot
    const int nh  = w >> 1;            // n half
    const int ml  = tid & 63;          // m lane

    __shared__ __align__(16) float xe[2][2 * QSL][8];   // 5.9 KB

    // fold block n-range [by*92, by*92+92): lanes along n -> coalesced fwd+mirror
    for (int j = tid; j < 2 * 8 * (2 * QSL); j += 256) {
        int s   = j / (8 * 2 * QSL);
        int r   = j - s * (8 * 2 * QSL);
        int ch  = r / (2 * QSL);
        int nnb = r - ch * (2 * QSL);
        int n   = by * (2 * QSL) + nnb;
        int k   = bx * 2 + s; if (k > 360) k = 360;
        float v = 0.f;
        if (n <= 360) {
            const float* __restrict__ row = x + ((size_t)ch * NLAT + k) * NLON;
            float a = row[n];
            float b = (n == 0) ? 0.f : row[NLON - n];   // n=360 -> 2x; fixup below
            v = a + b;
        }
        xe[s][nnb][ch] = v;
    }
    __syncthreads();

    const int nq  = by * 2 + nh;
    const int n0  = nq * QSL;
    const int cnt = (n0 < NLAT) ? min(QSL, NLAT - n0) : 0;   // 46.. / 39
    const int rb  = nh * QSL;          // xe row base for this wave

    float P0[6], P1[6], c2[6];
#pragma unroll
    for (int q = 0; q < 6; ++q) {
        int m = ml + 64 * q; if (m > 360) m = 360;      // clamp; store guarded
        int t0 = (n0 * m) % NLON;                       // exact integer reduction
        int t1 = t0 + m; if (t1 >= NLON) t1 -= NLON;
        P0[q] = __cosf((float)t0 * kAngF);
        P1[q] = __cosf((float)t1 * kAngF);
        c2[q] = 2.f * __cosf((float)m * kAngF);
    }

    float acc[6][8];
#pragma unroll
    for (int q = 0; q < 6; ++q)
#pragma unroll
        for (int b = 0; b < 8; ++b) acc[q][b] = 0.f;

#pragma unroll 2
    for (int nn = 0; nn < cnt; ++nn) {
        float4 e0 = *(const float4*)&xe[ks][rb + nn][0];    // uniform broadcast
        float4 e1 = *(const float4*)&xe[ks][rb + nn][4];
#pragma unroll
        for (int q = 0; q < 6; ++q) {
            float f = P0[q];
            acc[q][0] += f * e0.x;  acc[q][1] += f * e0.y;
            acc[q][2] += f * e0.z;  acc[q][3] += f * e0.w;
            acc[q][4] += f * e1.x;  acc[q][5] += f * e1.y;
            acc[q][6] += f * e1.z;  acc[q][7] += f * e1.w;
            float Pn = c2[q] * P1[q] - P0[q];
            P0[q] = P1[q];
            P1[q] = Pn;
        }
    }

    if (nq == NSL - 1) {     // n=360 (nn=38): weight 1*(-1)^m*(2x) -> 0.5
        float4 e0 = *(const float4*)&xe[ks][rb + 38][0];
        float4 e1 = *(const float4*)&xe[ks][rb + 38][4];
#pragma unroll
        for (int q = 0; q < 6; ++q) {
            int m = ml + 64 * q;
            float h = 0.5f * ((m & 1) ? -1.f : 1.f);
            acc[q][0] -= h * e0.x;  acc[q][1] -= h * e0.y;
            acc[q][2] -= h * e0.z;  acc[q][3] -= h * e0.w;
            acc[q][4] -= h * e1.x;  acc[q][5] -= h * e1.y;
            acc[q][6] -= h * e1.z;  acc[q][7] -= h * e1.w;
        }
    }

    const int k = bx * 2 + ks;
    if (k <= 360) {
        float* __restrict__ sl = slices + (size_t)nq * SL_F;
#pragma unroll
        for (int q = 0; q < 6; ++q) {
            int m = ml + 64 * q;
            if (m > 360) continue;
            float4* o = (float4*)(sl + ((size_t)k * MMAX + m) * 8);
            o[0] = make_float4(acc[q][0] * kAngF, acc[q][1] * kAngF,
                               acc[q][2] * kAngF, acc[q][3] * kAngF);
            o[1] = make_float4(acc[q][4] * kAngF, acc[q][5] * kAngF,
                               acc[q][6] * kAngF, acc[q][7] * kAngF);
        }
    }
}

// ---------------- kernel 2: sum NSL slices + transpose [k][m] -> [m][k] --------
#define TK 16
#define TM 32
#define TSTRIDE 265                    // LDS row stride (floats), conflict-breaking
__global__ __launch_bounds__(256) void k_redT(const float* __restrict__ slices,
                                              float* __restrict__ xt) {
    const int k0  = blockIdx.x * TK;
    const int m0  = blockIdx.y * TM;
    const int tid = threadIdx.x;

    __shared__ __align__(16) float t[TK * TSTRIDE];   // 17 KB

    for (int j = tid; j < TK * TM * 2; j += 256) {    // float4 units
        int kk = j / (TM * 2);
        int r  = j - kk * (TM * 2);
        int mm = r >> 1, h = r & 1;
        int k = k0 + kk, m = m0 + mm;
        float4 s = make_float4(0.f, 0.f, 0.f, 0.f);
        if (k <= 360 && m <= 360) {
            size_t off = ((size_t)k * MMAX + m) * 2 + h;
            const float4* p = (const float4*)slices;
#pragma unroll
            for (int q = 0; q < NSL; ++q) {
                float4 a = p[off + (size_t)q * (SL_F / 4)];
                s.x += a.x; s.y += a.y; s.z += a.z; s.w += a.w;
            }
        }
        *(float4*)&t[kk * TSTRIDE + mm * 8 + h * 4] = s;
    }
    __syncthreads();

    for (int j = tid; j < TM * TK * 2; j += 256) {
        int mm = j / (TK * 2);
        int r  = j - mm * (TK * 2);
        int kk = r >> 1, h = r & 1;
        int k = k0 + kk, m = m0 + mm;
        if (k <= 360 && m <= 360) {
            float4 v = *(const float4*)&t[kk * TSTRIDE + mm * 8 + h * 4];
            ((float4*)xt)[((size_t)m * MMAX + k) * 2 + h] = v;
        }
    }
}

// ---------------- kernel 3: contraction (unchanged, proven) --------------
__global__ __launch_bounds__(256) void k_contract4(const float* __restrict__ W,
                                                   const float* __restrict__ xt,
                                                   float* __restrict__ out) {
    const int lt   = blockIdx.x;
    const int m    = blockIdx.y;
    const int l0   = lt * 32;
    const int tid  = threadIdx.x;

    if (l0 + 31 < m) {
        int l = l0 + (tid >> 3), bc = tid & 7;
        out[(bc * LMAX + l) * MMAX + m] = 0.f;
        return;
    }

    const int kk = tid & 31, lq = tid >> 5;
    const int lb = l0 + lq * 4;

    int lr[4];
#pragma unroll
    for (int j = 0; j < 4; ++j) {
        int l = lb + j;
        if (l < m)        l = m;
        if (l > LMAX - 1) l = LMAX - 1;
        lr[j] = l;
    }

    const float* __restrict__ Wm = W + (size_t)m * (LMAX * NLAT);
    const float* __restrict__ r0 = Wm + lr[0] * NLAT + kk;
    const float* __restrict__ r1 = Wm + lr[1] * NLAT + kk;
    const float* __restrict__ r2 = Wm + lr[2] * NLAT + kk;
    const float* __restrict__ r3 = Wm + lr[3] * NLAT + kk;

    float wv[12][4];
#pragma unroll
    for (int t = 0; t < 11; ++t) {
        wv[t][0] = r0[t * 32];
        wv[t][1] = r1[t * 32];
        wv[t][2] = r2[t * 32];
        wv[t][3] = r3[t * 32];
    }
    {
        int kq = 11 * 32 + kk;
        int kc = (kq <= 360) ? kq : 360;
        wv[11][0] = Wm[lr[0] * NLAT + kc];
        wv[11][1] = Wm[lr[1] * NLAT + kc];
        wv[11][2] = Wm[lr[2] * NLAT + kc];
        wv[11][3] = Wm[lr[3] * NLAT + kc];
        if (kq > 360) { wv[11][0] = wv[11][1] = wv[11][2] = wv[11][3] = 0.f; }
    }

    float v[32];
#pragma unroll
    for (int i = 0; i < 32; ++i) v[i] = 0.f;

    const float4* __restrict__ xt4 = (const float4*)xt;
#pragma unroll
    for (int t = 0; t < 12; ++t) {
        int kq = t * 32 + kk;
        int kc = (kq <= 360) ? kq : 360;
        int xb = (m * NLAT + kc) * 2;
        float4 x0 = xt4[xb], x1 = xt4[xb + 1];
#pragma unroll
        for (int j = 0; j < 4; ++j) {
            float wj = wv[t][j];
            v[j*8 + 0] += wj * x0.x;  v[j*8 + 1] += wj * x0.y;
            v[j*8 + 2] += wj * x0.z;  v[j*8 + 3] += wj * x0.w;
            v[j*8 + 4] += wj * x1.x;  v[j*8 + 5] += wj * x1.y;
            v[j*8 + 6] += wj * x1.z;  v[j*8 + 7] += wj * x1.w;
        }
    }

#define RSTEP(MASK, CNT) { const bool hi = (kk & MASK) != 0; \
    _Pragma("unroll") \
    for (int i = 0; i < CNT; ++i) { \
        float keep = hi ? v[i + CNT] : v[i]; \
        float send = hi ? v[i] : v[i + CNT]; \
        v[i] = keep + __shfl_xor(send, MASK); } }
    RSTEP(16, 16) RSTEP(8, 8) RSTEP(4, 4) RSTEP(2, 2) RSTEP(1, 1)
#undef RSTEP

    int j  = kk >> 3;
    int bc = kk & 7;
    int l  = l0 + lq * 4 + j;
    if (l >= LMAX) return;
    float r = (l < m) ? 0.f : v[0];
    out[(bc * LMAX + l) * MMAX + m] = r;
}

// ---------------- legacy fallback (cplx hedge / small ws) ----------------
template<int CPLX>
__global__ __launch_bounds__(192) void k_dft_leg(const float* __restrict__ x,
                                                 float* __restrict__ xt,
                                                 int mb, int mc) {
    const int k    = blockIdx.x;
    const int half = blockIdx.y;
    const int tid  = threadIdx.x;

    __shared__ __align__(16) float  xr[8 * 724];
    __shared__ __align__(16) float2 exo[8 * 362];

    {
        const float4* __restrict__ x4 = (const float4*)x;
        for (int j = tid; j < 8 * 180; j += 192) {
            int b = j / 180, q = j - b * 180;
            ((float4*)&xr[b * 724])[q] = x4[(b * NLAT + k) * 180 + q];
        }
        if (tid < 8) ((float4*)&xr[tid * 724])[180] = make_float4(0.f, 0.f, 0.f, 0.f);
    }
    __syncthreads();

    for (int j = tid; j < 8 * NLAT; j += 192) {
        int b = j / NLAT, n = j - b * NLAT;
        float xa  = xr[b * 724 + n];
        float xbv = xr[b * 724 + (NLON - n)];
        exo[b * 362 + n] = make_float2(xa + xbv, xa - xbv);
    }
    __syncthreads();

    const int  m_local = half * 192 + tid;
    const bool valid   = (m_local < mc);
    const int  m       = mb + (valid ? m_local : 0);

    float aRe[8], aIm[8];
#pragma unroll
    for (int b = 0; b < 8; ++b) { aRe[b] = 0.f; aIm[b] = 0.f; }

    int tacc = 0;
    for (int n = 0; n < NLAT; ++n) {
        float sn, cs;
        __sincosf((float)tacc * kAngF, &sn, &cs);
        float wgt = (n == 360) ? 0.5f : 1.0f;
        float fc = wgt * kAngF * cs;
        float fs = -wgt * kAngF * sn;
        tacc += m;
        if (tacc >= NLON) tacc -= NLON;
#pragma unroll
        for (int b = 0; b < 8; ++b) {
            float2 e = exo[b * 362 + n];
            aRe[b] += fc * e.x;
            if (CPLX) aIm[b] += fs * e.y;
        }
    }

    if (valid) {
        float4* __restrict__ xt4 = (float4*)xt;
        if (CPLX) {
            int base = (m_local * NLAT + k) * 4;
#pragma unroll
            for (int q = 0; q < 4; ++q)
                xt4[base + q] = make_float4(aRe[2*q], aIm[2*q], aRe[2*q+1], aIm[2*q+1]);
        } else {
            int base = (m_local * NLAT + k) * 2;
            xt4[base + 0] = make_float4(aRe[0], aRe[1], aRe[2], aRe[3]);
            xt4[base + 1] = make_float4(aRe[4], aRe[5], aRe[6], aRe[7]);
        }
    }
}

template<int CPLX>
__global__ __launch_bounds__(256) void k_contract_leg(const float* __restrict__ W,
                                                      const float* __restrict__ xt,
                                                      float* __restrict__ out,
                                                      int mb) {
    const int lt   = blockIdx.x;
    const int mloc = blockIdx.y;
    const int m    = mb + mloc;
    const int l0   = lt * 32;
    const int tid  = threadIdx.x;

    if (l0 + 31 < m) {
        int l = l0 + (tid >> 3), bc = tid & 7;
        int idx = (bc * LMAX + l) * MMAX + m;
        if (CPLX) ((float2*)out)[idx] = make_float2(0.f, 0.f);
        else      out[idx] = 0.f;
        return;
    }

    const int kk = tid & 31, lq = tid >> 5;
    const int lb = l0 + lq * 4;

    int lr[4];
#pragma unroll
    for (int j = 0; j < 4; ++j) {
        int l = lb + j;
        if (l < m)        l = m;
        if (l > LMAX - 1) l = LMAX - 1;
        lr[j] = l;
    }

    const float* __restrict__ Wm = W + (size_t)m * (LMAX * NLAT);
    const float4* __restrict__ xt4 = (const float4*)xt;
    constexpr int NX = CPLX ? 4 : 2;
    constexpr int NV = CPLX ? 64 : 32;

    float v[NV];
#pragma unroll
    for (int i = 0; i < NV; ++i) v[i] = 0.f;

#define CLOAD(T, WV, XV) { \
    int kq = (T) * 32 + kk; \
    int kc = (kq < NLAT) ? kq : (NLAT - 1); \
    _Pragma("unroll") \
    for (int j = 0; j < 4; ++j) WV[j] = Wm[lr[j] * NLAT + kc]; \
    int xb = (mloc * NLAT + kc) * NX; \
    _Pragma("unroll") \
    for (int q = 0; q < NX; ++q) XV[q] = xt4[xb + q]; \
    if (kq >= NLAT) { WV[0] = WV[1] = WV[2] = WV[3] = 0.f; } }

#define CFMA(WV, XV) { \
    _Pragma("unroll") \
    for (int j = 0; j < 4; ++j) { \
        float wj = WV[j]; \
        if (CPLX) { \
            _Pragma("unroll") \
            for (int q = 0; q < 4; ++q) { \
                v[j*16 + (2*q  )*2 + 0] += wj * XV[q].x; \
                v[j*16 + (2*q  )*2 + 1] += wj * XV[q].y; \
                v[j*16 + (2*q+1)*2 + 0] += wj * XV[q].z; \
                v[j*16 + (2*q+1)*2 + 1] += wj * XV[q].w; \
            } \
        } else { \
            v[j*8 + 0] += wj * XV[0].x;  v[j*8 + 1] += wj * XV[0].y; \
            v[j*8 + 2] += wj * XV[0].z;  v[j*8 + 3] += wj * XV[0].w; \
            v[j*8 + 4] += wj * XV[1].x;  v[j*8 + 5] += wj * XV[1].y; \
            v[j*8 + 6] += wj * XV[1].z;  v[j*8 + 7] += wj * XV[1].w; \
        } \
    } }

    float  w0[4], w1[4], wn[4];
    float4 x0[NX], x1[NX], xn[NX];
    CLOAD(0, w0, x0)
    CLOAD(1, w1, x1)
#pragma unroll
    for (int t = 0; t < 12; ++t) {
        if (t < 10) CLOAD(t + 2, wn, xn)
        CFMA(w0, x0)
#pragma unroll
        for (int j = 0; j < 4; ++j) w0[j] = w1[j];
#pragma unroll
        for (int q = 0; q < NX; ++q) x0[q] = x1[q];
        if (t < 10) {
#pragma unroll
            for (int j = 0; j < 4; ++j) w1[j] = wn[j];
#pragma unroll
            for (int q = 0; q < NX; ++q) x1[q] = xn[q];
        }
    }
#undef CLOAD
#undef CFMA

#define RSTEP(MASK, CNT) { const bool hi = (kk & MASK) != 0; \
    _Pragma("unroll") \
    for (int i = 0; i < CNT; ++i) { \
        float keep = hi ? v[i + CNT] : v[i]; \
        float send = hi ? v[i] : v[i + CNT]; \
        v[i] = keep + __shfl_xor(send, MASK); } }
    if (CPLX) {
        RSTEP(16, 32) RSTEP(8, 16) RSTEP(4, 8) RSTEP(2, 4) RSTEP(1, 2)
    } else {
        RSTEP(16, 16) RSTEP(8, 8) RSTEP(4, 4) RSTEP(2, 2) RSTEP(1, 1)
    }
#undef RSTEP

    int j  = kk >> 3;
    int bc = kk & 7;
    int l  = l0 + lq * 4 + j;
    if (l >= LMAX) return;
    int idx = (bc * LMAX + l) * MMAX + m;
    if (CPLX) {
        float2 r = make_float2(v[0], v[1]);
        if (l < m) r = make_float2(0.f, 0.f);
        ((float2*)out)[idx] = r;
    } else {
        float r = (l < m) ? 0.f : v[0];
        out[idx] = r;
    }
}

extern "C" void kernel_launch(void* const* d_in, const int* in_sizes, int n_in,
                              void* d_out, int out_size, void* d_ws, size_t ws_size,
                              hipStream_t stream) {
    const float* x = (const float*)d_in[0];
    const float* W = (const float*)d_in[1];
    float* ws = (float*)d_ws;

    const int n_complex = 8 * LMAX * MMAX;            // 1,039,680
    const int cplx = (out_size >= 2 * n_complex) ? 1 : 0;

    if (!cplx && ws_size >= (size_t)(NSL + 1) * SL_F * sizeof(float)) {
        float* slices = ws;
        float* xt     = ws + (size_t)NSL * SL_F;
        k_dft9<<<dim3(181, NSL / 2), dim3(256), 0, stream>>>(x, slices);
        k_redT<<<dim3(23, 12), dim3(256), 0, stream>>>(slices, xt);
        k_contract4<<<dim3(12, MMAX), dim3(256), 0, stream>>>(W, xt, (float*)d_out);
        return;
    }

    // hedge / fallback: legacy sincosf path (chunked if ws small)
    const int xs_per_mk = cplx ? 16 : 8;
    const size_t per_m_bytes = (size_t)NLAT * xs_per_mk * sizeof(float);
    int CM = (int)(ws_size / per_m_bytes);
    if (CM > MMAX) CM = MMAX;
    if (CM < 1)    CM = 1;
    for (int mbase = 0; mbase < MMAX; mbase += CM) {
        int mc = MMAX - mbase;
        if (mc > CM) mc = CM;
        if (cplx) {
            k_dft_leg<1><<<dim3(NLAT, (mc + 191) / 192), dim3(192), 0, stream>>>(
                x, ws, mbase, mc);
            k_contract_leg<1><<<dim3(12, mc), dim3(256), 0, stream>>>(W, ws, (float*)d_out, mbase);
        } else {
            k_dft_leg<0><<<dim3(NLAT, (mc + 191) / 192), dim3(192), 0, stream>>>(
                x, ws, mbase, mc);
            k_contract_leg<0><<<dim3(12, mc), dim3(256), 0, stream>>>(W, ws, (float*)d_out, mbase);
        }
    }
}